// Round 1
// baseline (324.670 us; speedup 1.0000x reference)
//
#include <hip/hip_runtime.h>
#include <stdint.h>

#define T_TOK 4096
#define DM    512
#define DFF   2048
#define NE    16
#define NSLOT (T_TOK * 2)

typedef __attribute__((ext_vector_type(8))) short  bf16x8;
typedef __attribute__((ext_vector_type(4))) float  f32x4;
typedef __attribute__((ext_vector_type(4))) unsigned short us4;
typedef __attribute__((ext_vector_type(8))) unsigned short us8;

static __device__ __forceinline__ unsigned short f2bf(float f) {
    unsigned int u = __float_as_uint(f);
    u += 0x7FFFu + ((u >> 16) & 1u);   // RNE
    return (unsigned short)(u >> 16);
}

// ---------------- router: fp32 logits, softmax, top-2 --------------------
__global__ __launch_bounds__(256) void router_kernel(
    const float* __restrict__ x, const float* __restrict__ rw,
    const float* __restrict__ rb, int* __restrict__ tok_e,
    float* __restrict__ tok_g)
{
    __shared__ float rws[NE * DM];            // 32 KB
    int tid = threadIdx.x;
    for (int i = 0; i < 8; ++i) {
        int idx = (tid + i * 256) * 4;
        *(f32x4*)&rws[idx] = *(const f32x4*)&rw[idx];
    }
    __syncthreads();

    int wid = tid >> 6, lane = tid & 63;
    int t = blockIdx.x * 4 + wid;

    float xv[8];
    const float* xp = x + (size_t)t * DM + lane * 8;
    *(f32x4*)&xv[0] = *(const f32x4*)xp;
    *(f32x4*)&xv[4] = *(const f32x4*)(xp + 4);

    float acc[NE];
    for (int e = 0; e < NE; ++e) {
        const float* wp = &rws[e * DM + lane * 8];
        float a = 0.f;
        for (int i = 0; i < 8; ++i) a += xv[i] * wp[i];
        acc[e] = a;
    }
    for (int e = 0; e < NE; ++e) {
        float v = acc[e];
        for (int off = 32; off > 0; off >>= 1) v += __shfl_xor(v, off);
        acc[e] = v + rb[e];                    // all lanes hold all logits
    }
    float m = acc[0];
    for (int e = 1; e < NE; ++e) m = fmaxf(m, acc[e]);
    float p[NE]; float s = 0.f;
    for (int e = 0; e < NE; ++e) { p[e] = expf(acc[e] - m); s += p[e]; }
    float inv = 1.f / s;
    int i0 = 0; float p0 = p[0];
    for (int e = 1; e < NE; ++e) if (p[e] > p0) { p0 = p[e]; i0 = e; }
    int i1 = (i0 == 0) ? 1 : 0; float p1 = p[i1];
    for (int e = 0; e < NE; ++e)
        if (e != i0 && p[e] > p1) { p1 = p[e]; i1 = e; }
    if (lane == 0) {
        tok_e[t * 2]     = i0;  tok_e[t * 2 + 1] = i1;
        tok_g[t * 2]     = p0 * inv;
        tok_g[t * 2 + 1] = p1 * inv;
    }
}

// ---------------- compaction: per-expert slot lists ----------------------
__global__ __launch_bounds__(256) void compact_kernel(
    const int* __restrict__ tok_e, const float* __restrict__ tok_g,
    int* __restrict__ slot_token, float* __restrict__ slot_gate,
    int* __restrict__ eoff /* [0..15]=offset, [16..31]=count */)
{
    __shared__ int cnt[NE], cur[NE], offs[NE];
    int tid = threadIdx.x;
    if (tid < NE) cnt[tid] = 0;
    __syncthreads();
    for (int t = tid; t < T_TOK; t += 256) {
        atomicAdd(&cnt[tok_e[t * 2]], 1);
        atomicAdd(&cnt[tok_e[t * 2 + 1]], 1);
    }
    __syncthreads();
    if (tid == 0) {
        int r = 0;
        for (int e = 0; e < NE; ++e) { offs[e] = r; cur[e] = r; r += cnt[e]; }
    }
    __syncthreads();
    if (tid < NE) { eoff[tid] = offs[tid]; eoff[NE + tid] = cnt[tid]; }
    for (int t = tid; t < T_TOK; t += 256) {
        for (int k = 0; k < 2; ++k) {
            int e = tok_e[t * 2 + k];
            int s = atomicAdd(&cur[e], 1);
            slot_token[s] = t;
            slot_gate[s]  = tok_g[t * 2 + k];
        }
    }
}

// ---------------- GEMM1: h = gelu(x_gathered @ w1^T + b1), bf16 out ------
__global__ __launch_bounds__(256) void gemm1_kernel(
    const float* __restrict__ x, const float* __restrict__ w1,
    const float* __restrict__ b1, const int* __restrict__ slot_token,
    const int* __restrict__ eoff, unsigned short* __restrict__ h)
{
    __shared__ unsigned short smem[18432];     // As[128][72] + Bs[128][72]
    __shared__ int tokrow[128];
    unsigned short* As = smem;
    unsigned short* Bs = smem + 9216;

    int e   = blockIdx.z;
    int off = eoff[e], cnt = eoff[NE + e];
    int mt  = blockIdx.y;
    if (mt * 128 >= cnt) return;
    int nB    = blockIdx.x * 128;
    int slot0 = off + mt * 128;
    int valid = cnt - mt * 128; if (valid > 128) valid = 128;

    int tid = threadIdx.x;
    if (tid < 128) {
        int s = slot0 + tid; if (s > NSLOT - 1) s = NSLOT - 1;
        tokrow[tid] = (tid < valid) ? slot_token[s] : 0;
    }
    __syncthreads();

    f32x4 acc[16];
    for (int i = 0; i < 16; ++i) acc[i] = (f32x4){0.f, 0.f, 0.f, 0.f};

    const float* wbase = w1 + ((size_t)e * DFF + nB) * DM;
    int wid = tid >> 6, lane = tid & 63;
    int wm = (wid & 1) * 64, wn = (wid >> 1) * 64;
    int q = lane >> 4, c = lane & 15;

    for (int kt = 0; kt < DM / 64; ++kt) {
        for (int i = 0; i < 8; ++i) {
            int u = tid + i * 256;
            int row = u >> 4, c4 = u & 15;
            f32x4 v = *(const f32x4*)(x + (size_t)tokrow[row] * DM + kt * 64 + c4 * 4);
            us4 a; a.x = f2bf(v.x); a.y = f2bf(v.y); a.z = f2bf(v.z); a.w = f2bf(v.w);
            *(us4*)&As[row * 72 + c4 * 4] = a;
            f32x4 w = *(const f32x4*)(wbase + (size_t)row * DM + kt * 64 + c4 * 4);
            us4 b; b.x = f2bf(w.x); b.y = f2bf(w.y); b.z = f2bf(w.z); b.w = f2bf(w.w);
            *(us4*)&Bs[row * 72 + c4 * 4] = b;
        }
        __syncthreads();
        for (int ks = 0; ks < 2; ++ks) {
            bf16x8 af[4], bfv[4];
            for (int i = 0; i < 4; ++i)
                af[i] = *(bf16x8*)&As[(wm + i * 16 + c) * 72 + ks * 32 + q * 8];
            for (int j = 0; j < 4; ++j)
                bfv[j] = *(bf16x8*)&Bs[(wn + j * 16 + c) * 72 + ks * 32 + q * 8];
            for (int i = 0; i < 4; ++i)
                for (int j = 0; j < 4; ++j)
                    acc[i * 4 + j] = __builtin_amdgcn_mfma_f32_16x16x32_bf16(
                        af[i], bfv[j], acc[i * 4 + j], 0, 0, 0);
        }
        __syncthreads();
    }

    // epilogue: bias + exact gelu, bounce through LDS for coalesced stores
    unsigned short* bounce = smem;             // [128][136]
    for (int i = 0; i < 4; ++i)
        for (int j = 0; j < 4; ++j) {
            int n = nB + wn + j * 16 + c;
            float bias = b1[e * DFF + n];
            f32x4 a = acc[i * 4 + j];
            for (int r = 0; r < 4; ++r) {
                int rowl = wm + i * 16 + q * 4 + r;
                float z = a[r] + bias;
                float g = 0.5f * z * (1.f + erff(z * 0.70710678118654752f));
                bounce[rowl * 136 + wn + j * 16 + c] = f2bf(g);
            }
        }
    __syncthreads();
    for (int i = 0; i < 8; ++i) {
        int row = (tid >> 4) + i * 16;
        if (row < valid) {
            us8 v = *(us8*)&bounce[row * 136 + (tid & 15) * 8];
            *(us8*)&h[(size_t)(slot0 + row) * DFF + nB + (tid & 15) * 8] = v;
        }
    }
}

// ---------------- GEMM2: out += gate * (h @ w2^T + b2) -------------------
__global__ __launch_bounds__(256) void gemm2_kernel(
    const unsigned short* __restrict__ h, const float* __restrict__ w2,
    const float* __restrict__ b2, const int* __restrict__ slot_token,
    const float* __restrict__ slot_gate, const int* __restrict__ eoff,
    float* __restrict__ out)
{
    __shared__ unsigned short smem[18432];
    __shared__ int   tokrow[128];
    __shared__ float grow[128];
    unsigned short* As = smem;
    unsigned short* Bs = smem + 9216;

    int e   = blockIdx.z;
    int off = eoff[e], cnt = eoff[NE + e];
    int mt  = blockIdx.y;
    if (mt * 128 >= cnt) return;
    int nB    = blockIdx.x * 128;
    int slot0 = off + mt * 128;
    int valid = cnt - mt * 128; if (valid > 128) valid = 128;

    int tid = threadIdx.x;
    if (tid < 128) {
        int s = slot0 + tid; if (s > NSLOT - 1) s = NSLOT - 1;
        tokrow[tid] = slot_token[s];
        grow[tid]   = slot_gate[s];
    }
    __syncthreads();

    f32x4 acc[16];
    for (int i = 0; i < 16; ++i) acc[i] = (f32x4){0.f, 0.f, 0.f, 0.f};

    const float* wbase = w2 + ((size_t)e * DM + nB) * DFF;
    int wid = tid >> 6, lane = tid & 63;
    int wm = (wid & 1) * 64, wn = (wid >> 1) * 64;
    int q = lane >> 4, c = lane & 15;

    for (int kt = 0; kt < DFF / 64; ++kt) {
        for (int i = 0; i < 4; ++i) {           // A: h already bf16
            int u = tid + i * 256;
            int row = u >> 3, c8 = u & 7;
            int s = slot0 + row; if (s > NSLOT - 1) s = NSLOT - 1;
            us8 v = *(const us8*)&h[(size_t)s * DFF + kt * 64 + c8 * 8];
            *(us8*)&As[row * 72 + c8 * 8] = v;
        }
        for (int i = 0; i < 8; ++i) {           // B: w2 fp32 -> bf16
            int u = tid + i * 256;
            int row = u >> 4, c4 = u & 15;
            f32x4 w = *(const f32x4*)(wbase + (size_t)row * DFF + kt * 64 + c4 * 4);
            us4 b; b.x = f2bf(w.x); b.y = f2bf(w.y); b.z = f2bf(w.z); b.w = f2bf(w.w);
            *(us4*)&Bs[row * 72 + c4 * 4] = b;
        }
        __syncthreads();
        for (int ks = 0; ks < 2; ++ks) {
            bf16x8 af[4], bfv[4];
            for (int i = 0; i < 4; ++i)
                af[i] = *(bf16x8*)&As[(wm + i * 16 + c) * 72 + ks * 32 + q * 8];
            for (int j = 0; j < 4; ++j)
                bfv[j] = *(bf16x8*)&Bs[(wn + j * 16 + c) * 72 + ks * 32 + q * 8];
            for (int i = 0; i < 4; ++i)
                for (int j = 0; j < 4; ++j)
                    acc[i * 4 + j] = __builtin_amdgcn_mfma_f32_16x16x32_bf16(
                        af[i], bfv[j], acc[i * 4 + j], 0, 0, 0);
        }
        __syncthreads();
    }

    for (int i = 0; i < 4; ++i)
        for (int j = 0; j < 4; ++j) {
            int n = nB + wn + j * 16 + c;
            float bias = b2[e * DM + n];
            for (int r = 0; r < 4; ++r) {
                int rowl = wm + i * 16 + q * 4 + r;
                if (rowl < valid) {
                    float y = acc[i * 4 + j][r] + bias;
                    atomicAdd(&out[(size_t)tokrow[rowl] * DM + n], grow[rowl] * y);
                }
            }
        }
}

extern "C" void kernel_launch(void* const* d_in, const int* in_sizes, int n_in,
                              void* d_out, int out_size, void* d_ws, size_t ws_size,
                              hipStream_t stream) {
    const float* x  = (const float*)d_in[0];
    const float* rw = (const float*)d_in[1];
    const float* rb = (const float*)d_in[2];
    const float* w1 = (const float*)d_in[3];
    const float* b1 = (const float*)d_in[4];
    const float* w2 = (const float*)d_in[5];
    const float* b2 = (const float*)d_in[6];
    float* out = (float*)d_out;

    char* ws = (char*)d_ws;
    unsigned short* h = (unsigned short*)ws;                 // 33.55 MB bf16
    size_t o = (size_t)NSLOT * DFF * 2;
    int*   tok_e      = (int*)(ws + o);   o += (size_t)NSLOT * 4;
    float* tok_g      = (float*)(ws + o); o += (size_t)NSLOT * 4;
    int*   slot_token = (int*)(ws + o);   o += (size_t)NSLOT * 4;
    float* slot_gate  = (float*)(ws + o); o += (size_t)NSLOT * 4;
    int*   eoff       = (int*)(ws + o);

    hipMemsetAsync(d_out, 0, (size_t)T_TOK * DM * 4, stream);
    router_kernel<<<T_TOK / 4, 256, 0, stream>>>(x, rw, rb, tok_e, tok_g);
    compact_kernel<<<1, 256, 0, stream>>>(tok_e, tok_g, slot_token, slot_gate, eoff);
    gemm1_kernel<<<dim3(DFF / 128, 32, NE), 256, 0, stream>>>(
        x, w1, b1, slot_token, eoff, h);
    gemm2_kernel<<<dim3(DM / 128, 32, NE), 256, 0, stream>>>(
        h, w2, b2, slot_token, slot_gate, eoff, out);
}